// Round 9
// baseline (176.498 us; speedup 1.0000x reference)
//
#include <hip/hip_runtime.h>
#include <math.h>

// CRF mean-field, fully factorized — NO O(N^2) pass.
// MULTI-LAUNCH, 8 dispatches: phaseA, init, conv x5 (fuse folded in), out.
// k_fuse eliminated: conv blocks unsafeAtomicAdd their weighted output
// (s1*M*conv / s2*conv) into per-iteration comb[4] accumulators (fire-and-
// forget hw f32 atomics, scattered addresses — NOT the R3/R4 same-address
// spin-RMW pathology). Next conv's staging computes softmax/u inline from
// 4 comb rows. Per-iteration comb buffers (zeroed once in k_init) avoid
// zeroing races; kernel boundaries provide coherence for the atomic results.
// Bilateral kernel rank-28 Taylor basis (degree 6), separable 3-D Gaussian
// convs, 5 mean-field iterations. N = 32*16*16 = 8192, C = 4.

constexpr int   NT    = 8192;
constexpr float LOG2E = 1.4426950408889634f;
constexpr float SQL2E = 1.2011224087864498f;     // sqrt(log2 e)
constexpr float INVA  = 0.2f * SQL2E;            // spatial prescale

// W rows (NT floats each):
//   0..27 : M[ab]   32..35 : u1[c]   36..39 : u2[c]   40 : s1   41 : s2
//   42..69 : norm-pass CV (phaseA only)
//   70..89 : comb accumulators, 5 iterations x 4 channels
constexpr int R_M = 0, R_U1 = 32, R_U2 = 36, R_S1 = 40, R_S2 = 41, R_CV = 42;
constexpr int R_CB = 70;

static __device__ __forceinline__ float ex2(float x) {
    return __builtin_amdgcn_exp2f(x);
}

__constant__ float INVSQF[7] = {1.f, 1.f, 0.70710678f, 0.40824829f,
                                0.20412415f, 0.09128709f, 0.03726780f};
// ab -> (a,b) enumeration: for k=0..6, a=k..0, b=k-a (must match contract order)
__constant__ int AB_A[28] = {0, 1,0, 2,1,0, 3,2,1,0, 4,3,2,1,0,
                             5,4,3,2,1,0, 6,5,4,3,2,1,0};
__constant__ int AB_B[28] = {0, 0,1, 0,1,2, 0,1,2,3, 0,1,2,3,4,
                             0,1,2,3,4,5, 0,1,2,3,4,5,6};

// ---------------- separable 3-D Gaussian conv, 512-thread version -----------
// SP staged as SP[(n>>4)*17 + (n&15)]; caller stages, we sync first.
// ATOMIC=0: out[n] = w0*w1*acc (store).  ATOMIC=1: unsafeAtomicAdd instead.
template <int ATOMIC>
static __device__ __forceinline__ void conv3d_out512(float* SP,
                                                     float* __restrict__ outp,
                                                     const float* w0,
                                                     const float* w1,
                                                     int tid) {
    float g32[32];
#pragma unroll
    for (int d = 0; d < 32; d++) { float t = d * INVA; g32[d] = ex2(-0.5f*t*t); }
    __syncthreads();
    // z-pass: 512 rows (x,y), one per thread, stride 17
    {
        int r = tid;
        float v[16], acc[16];
#pragma unroll
        for (int z = 0; z < 16; z++) { v[z] = SP[r*17 + z]; acc[z] = 0.f; }
#pragma unroll
        for (int zp = 0; zp < 16; zp++)
#pragma unroll
            for (int z = 0; z < 16; z++) {
                int d = (z > zp) ? (z - zp) : (zp - z);
                acc[z] = fmaf(g32[d], v[zp], acc[z]);
            }
#pragma unroll
        for (int z = 0; z < 16; z++) SP[r*17 + z] = acc[z];
    }
    __syncthreads();
    // y-pass: 512 rows (x,z), one per thread, stride 17 between y's
    {
        int x = tid >> 4, z = tid & 15;
        int base = x * 272 + z;
        float v[16], acc[16];
#pragma unroll
        for (int y = 0; y < 16; y++) { v[y] = SP[base + y*17]; acc[y] = 0.f; }
#pragma unroll
        for (int yp = 0; yp < 16; yp++)
#pragma unroll
            for (int y = 0; y < 16; y++) {
                int d = (y > yp) ? (y - yp) : (yp - y);
                acc[y] = fmaf(g32[d], v[yp], acc[y]);
            }
#pragma unroll
        for (int y = 0; y < 16; y++) SP[base + y*17] = acc[y];
    }
    __syncthreads();
    // x-pass: 256 columns (y,z), 2 threads/column; h wave-uniform (tid>>8)
    // so all g32 indices stay compile-time constants (no scratch spill).
    {
        int c = tid & 255, h = tid >> 8;
        int base = (c >> 4) * 17 + (c & 15);     // 17*y + z
        float v[32];
#pragma unroll
        for (int xp = 0; xp < 32; xp++) v[xp] = SP[base + xp*272];
        float acc[16];
#pragma unroll
        for (int x0 = 0; x0 < 16; x0++) acc[x0] = 0.f;
        if (h == 0) {
#pragma unroll
            for (int xp = 0; xp < 32; xp++)
#pragma unroll
                for (int x0 = 0; x0 < 16; x0++) {
                    int d = (x0 > xp) ? (x0 - xp) : (xp - x0);
                    acc[x0] = fmaf(g32[d], v[xp], acc[x0]);
                }
#pragma unroll
            for (int x0 = 0; x0 < 16; x0++) {
                int n = x0*256 + c;
                float w = w0 ? w0[n] : 1.f;
                if (w1) w *= w1[n];
                if (ATOMIC) unsafeAtomicAdd(&outp[n], w * acc[x0]);
                else        outp[n] = w * acc[x0];
            }
        } else {
#pragma unroll
            for (int xp = 0; xp < 32; xp++)
#pragma unroll
                for (int x0 = 0; x0 < 16; x0++) {
                    int x = x0 + 16;
                    int d = (x > xp) ? (x - xp) : (xp - x);
                    acc[x0] = fmaf(g32[d], v[xp], acc[x0]);
                }
#pragma unroll
            for (int x0 = 0; x0 < 16; x0++) {
                int n = (x0+16)*256 + c;
                float w = w0 ? w0[n] : 1.f;
                if (w1) w *= w1[n];
                if (ATOMIC) unsafeAtomicAdd(&outp[n], w * acc[x0]);
                else        outp[n] = w * acc[x0];
            }
        }
    }
}

// ---------------- phase A: basis + norm conv (premul M); spare blocks: s2 ---
__global__ __launch_bounds__(512) void k_phaseA(const float* __restrict__ feat,
                                                float* __restrict__ W) {
    __shared__ float SP[512 * 17];
    const int bid = blockIdx.x, tid = threadIdx.x;
    if (bid < 28) {
        const int a = AB_A[bid], b = AB_B[bid];
        const float ca = INVSQF[a], cb = INVSQF[b];
        for (int s = tid; s < NT; s += 512) {
            float g0 = feat[s] * 0.2f, g1 = feat[NT + s] * 0.2f;
            float eg = ex2(-0.5f * LOG2E * (g0*g0 + g1*g1));
            float pa = 1.f;
            for (int i = 0; i < a; i++) pa *= g0;    // a,b wave-uniform
            float pb = 1.f;
            for (int i = 0; i < b; i++) pb *= g1;
            float v = eg * pa * ca * pb * cb;
            W[(R_M + bid)*NT + s] = v;
            SP[(s >> 4)*17 + (s & 15)] = v;
        }
        conv3d_out512<0>(SP, W + (R_CV + bid)*NT, W + (R_M + bid)*NT, nullptr, tid);
    } else {
        // blocks 28..31: closed-form scale2 (exact separable product)
#pragma unroll
        for (int i = 0; i < 4; i++) {
            int n = (bid - 28) * 2048 + i*512 + tid;
            int x = n >> 8, y = (n >> 4) & 15, z = n & 15;
            float Sx = 0.f, Sy = 0.f, Sz = 0.f;
            for (int j = 0; j < 32; j++) { float d = (float)(x-j)*INVA; Sx += ex2(-0.5f*d*d); }
            for (int j = 0; j < 16; j++) { float d = (float)(y-j)*INVA; Sy += ex2(-0.5f*d*d); }
            for (int j = 0; j < 16; j++) { float d = (float)(z-j)*INVA; Sz += ex2(-0.5f*d*d); }
            W[R_S2*NT + n] = rsqrtf(Sx * Sy * Sz);
        }
    }
}

// ---------------- init: s1, q0, u1, u2; zero the 20 comb rows ---------------
__global__ __launch_bounds__(256) void k_init(float* __restrict__ W,
                                              const float* __restrict__ lu) {
    int n = blockIdx.x * 256 + threadIdx.x;
    float rs = 0.f;
#pragma unroll
    for (int ab = 0; ab < 28; ab++)
        rs += W[(R_CV+ab)*NT + n];            // pre-multiplied by M in phaseA
    float s1 = rsqrtf(rs);
    float s2 = W[R_S2*NT + n];
    W[R_S1*NT + n] = s1;
    float l0 = lu[n], l1 = lu[NT+n], l2 = lu[2*NT+n], l3 = lu[3*NT+n];
    float mx = fmaxf(fmaxf(l0,l1), fmaxf(l2,l3));
    float q0 = __expf(l0-mx), q1 = __expf(l1-mx), q2 = __expf(l2-mx), q3 = __expf(l3-mx);
    float inv = 1.f / (q0+q1+q2+q3);
    q0*=inv; q1*=inv; q2*=inv; q3*=inv;
    W[(R_U1+0)*NT+n]=q0*s1; W[(R_U1+1)*NT+n]=q1*s1; W[(R_U1+2)*NT+n]=q2*s1; W[(R_U1+3)*NT+n]=q3*s1;
    W[(R_U2+0)*NT+n]=q0*s2; W[(R_U2+1)*NT+n]=q1*s2; W[(R_U2+2)*NT+n]=q2*s2; W[(R_U2+3)*NT+n]=q3*s2;
    // zero comb accumulators (5 iterations x 4 channels), one point per thread
#pragma unroll
    for (int k = 0; k < 20; k++) W[(R_CB + k)*NT + n] = 0.f;
}

// ---------------- iteration conv: stage (inline softmax for it>0),
//                  conv, atomic-accumulate into comb[it] -------------------
__global__ __launch_bounds__(512) void k_conv(float* __restrict__ W,
        const float* __restrict__ lu, const float* __restrict__ compat, int it) {
    __shared__ float SP[512 * 17];
    const int idx = blockIdx.x;
    const int tid = threadIdx.x;
    const bool spat = (idx >= 112);
    const int ch = spat ? (idx - 112) : (idx & 3);

    if (it == 0) {
        // staging from init's u rows (float4)
        if (!spat) {
            const float4* M4 = (const float4*)(W + (R_M + (idx >> 2))*NT);
            const float4* U4 = (const float4*)(W + (R_U1 + ch)*NT);
#pragma unroll
            for (int i = 0; i < 4; i++) {
                int s4 = tid + i*512;
                float4 m = M4[s4], u = U4[s4];
                int s = s4 << 2;
                int base = (s >> 4)*17 + (s & 15);
                SP[base+0] = m.x*u.x; SP[base+1] = m.y*u.y;
                SP[base+2] = m.z*u.z; SP[base+3] = m.w*u.w;
            }
        } else {
            const float4* U4 = (const float4*)(W + (R_U2 + ch)*NT);
#pragma unroll
            for (int i = 0; i < 4; i++) {
                int s4 = tid + i*512;
                float4 u = U4[s4];
                int s = s4 << 2;
                int base = (s >> 4)*17 + (s & 15);
                SP[base+0] = u.x; SP[base+1] = u.y; SP[base+2] = u.z; SP[base+3] = u.w;
            }
        }
    } else {
        // staging with inline fuse: softmax(lu - compat*comb_prev) -> u
        const float* cb = W + (R_CB + (it-1)*4)*NT;
        const float* srow = spat ? (W + R_S2*NT) : (W + R_S1*NT);
        const float* Mr = W + (R_M + (idx >> 2))*NT;   // unused when spat
        float cmp[16];
#pragma unroll
        for (int i = 0; i < 16; i++) cmp[i] = compat[i];
#pragma unroll
        for (int i = 0; i < 16; i++) {
            int s = tid + i*512;
            float c0 = cb[s],      c1 = cb[NT+s],
                  c2 = cb[2*NT+s], c3 = cb[3*NT+s];
            float q[4];
#pragma unroll
            for (int o = 0; o < 4; o++) {
                float upd = 0.f;
                upd = fmaf(cmp[o*4+0], c0, upd);
                upd = fmaf(cmp[o*4+1], c1, upd);
                upd = fmaf(cmp[o*4+2], c2, upd);
                upd = fmaf(cmp[o*4+3], c3, upd);
                q[o] = lu[o*NT+s] - upd;
            }
            float mx = fmaxf(fmaxf(q[0],q[1]), fmaxf(q[2],q[3]));
            float sum = 0.f;
#pragma unroll
            for (int c = 0; c < 4; c++) { q[c] = __expf(q[c]-mx); sum += q[c]; }
            // ch is wave-uniform: explicit select (no runtime-indexed array)
            float qc = (ch==0) ? q[0] : (ch==1) ? q[1] : (ch==2) ? q[2] : q[3];
            float u = (qc / sum) * srow[s];
            SP[(s >> 4)*17 + (s & 15)] = spat ? u : (Mr[s] * u);
        }
    }
    // conv + weighted atomic accumulate into comb[it]
    float* combp = W + (R_CB + it*4 + ch)*NT;
    if (!spat)
        conv3d_out512<1>(SP, combp, W + (R_M + (idx >> 2))*NT, W + R_S1*NT, tid);
    else
        conv3d_out512<1>(SP, combp, W + R_S2*NT, nullptr, tid);
}

// ---------------- out: final softmax from comb[4] ---------------------------
__global__ __launch_bounds__(256) void k_out(const float* __restrict__ W,
        const float* __restrict__ lu, const float* __restrict__ compat,
        float* __restrict__ out) {
    int n = blockIdx.x * 256 + threadIdx.x;
    const float* cb = W + (R_CB + 16)*NT;
    float c0 = cb[n], c1 = cb[NT+n], c2 = cb[2*NT+n], c3 = cb[3*NT+n];
    float q[4];
#pragma unroll
    for (int o = 0; o < 4; o++) {
        float upd = 0.f;
        upd = fmaf(compat[o*4+0], c0, upd);
        upd = fmaf(compat[o*4+1], c1, upd);
        upd = fmaf(compat[o*4+2], c2, upd);
        upd = fmaf(compat[o*4+3], c3, upd);
        q[o] = lu[o*NT+n] - upd;
    }
    float mx = fmaxf(fmaxf(q[0],q[1]), fmaxf(q[2],q[3]));
    float sum = 0.f;
#pragma unroll
    for (int c = 0; c < 4; c++) { q[c] = __expf(q[c]-mx); sum += q[c]; }
    float inv = 1.f / sum;
#pragma unroll
    for (int c = 0; c < 4; c++) out[c*NT+n] = q[c] * inv;
}

// ---------------------------------------------------------------- driver
extern "C" void kernel_launch(void* const* d_in, const int* in_sizes, int n_in,
                              void* d_out, int out_size, void* d_ws, size_t ws_size,
                              hipStream_t stream) {
    const float* lu     = (const float*)d_in[0];
    const float* feat   = (const float*)d_in[1];
    const float* compat = (const float*)d_in[2];
    float* out = (float*)d_out;
    float* W   = (float*)d_ws;     // needs 90*NT*4 = 2.95 MB

    k_phaseA<<<dim3(32),  dim3(512), 0, stream>>>(feat, W);   // basis+norm conv+s2
    k_init  <<<dim3(32),  dim3(256), 0, stream>>>(W, lu);     // s1,q0,u; zero combs
    for (int it = 0; it < 5; it++)
        k_conv<<<dim3(116), dim3(512), 0, stream>>>(W, lu, compat, it);
    k_out   <<<dim3(32),  dim3(256), 0, stream>>>(W, lu, compat, out);
}

// Round 10
// 158.040 us; speedup vs baseline: 1.1168x; 1.1168x over previous
//
#include <hip/hip_runtime.h>
#include <math.h>

// CRF mean-field, fully factorized — NO O(N^2) pass.
// MULTI-LAUNCH, 12 dispatches (structural minimum — R9 proved fuse-via-atomics
// regresses: cross-XCD atomics execute serialized at the coherence point,
// +9 us/conv. R2-R5 proved fences/sc1 likewise. Kernel boundaries are the only
// cheap cross-XCD coherence on MI355X).
// Conv epilogue pre-multiplies s1*M / s2 so k_fuse is a plain 29-term sum;
// fuse/init are float4-vectorized (4 pts/thread, same per-point FP order).
// Bilateral kernel rank-28 Taylor basis (degree 6), separable 3-D Gaussian
// convs, 5 mean-field iterations. N = 32*16*16 = 8192, C = 4.

constexpr int   NT    = 8192;
constexpr int   NQ    = NT / 4;                  // float4 elements per row
constexpr float LOG2E = 1.4426950408889634f;
constexpr float SQL2E = 1.2011224087864498f;     // sqrt(log2 e)
constexpr float INVA  = 0.2f * SQL2E;            // spatial prescale

// W rows (NT floats each):
//   0..27 : M[ab]   32..35 : u1[c]   36..39 : u2[c]
//   40 : scale1   41 : scale2   42..157 : conv outputs (pre-multiplied)
constexpr int R_M = 0, R_U1 = 32, R_U2 = 36, R_S1 = 40, R_S2 = 41, R_CV = 42;

static __device__ __forceinline__ float ex2(float x) {
    return __builtin_amdgcn_exp2f(x);
}

__constant__ float INVSQF[7] = {1.f, 1.f, 0.70710678f, 0.40824829f,
                                0.20412415f, 0.09128709f, 0.03726780f};
// ab -> (a,b) enumeration: for k=0..6, a=k..0, b=k-a (must match contract order)
__constant__ int AB_A[28] = {0, 1,0, 2,1,0, 3,2,1,0, 4,3,2,1,0,
                             5,4,3,2,1,0, 6,5,4,3,2,1,0};
__constant__ int AB_B[28] = {0, 0,1, 0,1,2, 0,1,2,3, 0,1,2,3,4,
                             0,1,2,3,4,5, 0,1,2,3,4,5,6};

// ---------------- separable 3-D Gaussian conv, 512-thread version -----------
// SP staged as SP[(n>>4)*17 + (n&15)]; caller stages, we sync first.
// Epilogue: out(n) = wrow0[n]*wrow1[n]*acc  (wrow1 may be null -> 1.0).
static __device__ __forceinline__ void conv3d_store512(float* SP,
                                                       float* __restrict__ outp,
                                                       const float* w0,
                                                       const float* w1,
                                                       int tid) {
    float g32[32];
#pragma unroll
    for (int d = 0; d < 32; d++) { float t = d * INVA; g32[d] = ex2(-0.5f*t*t); }
    __syncthreads();
    // z-pass: 512 rows (x,y), one per thread, stride 17
    {
        int r = tid;
        float v[16], acc[16];
#pragma unroll
        for (int z = 0; z < 16; z++) { v[z] = SP[r*17 + z]; acc[z] = 0.f; }
#pragma unroll
        for (int zp = 0; zp < 16; zp++)
#pragma unroll
            for (int z = 0; z < 16; z++) {
                int d = (z > zp) ? (z - zp) : (zp - z);
                acc[z] = fmaf(g32[d], v[zp], acc[z]);
            }
#pragma unroll
        for (int z = 0; z < 16; z++) SP[r*17 + z] = acc[z];
    }
    __syncthreads();
    // y-pass: 512 rows (x,z), one per thread, stride 17 between y's
    {
        int x = tid >> 4, z = tid & 15;
        int base = x * 272 + z;
        float v[16], acc[16];
#pragma unroll
        for (int y = 0; y < 16; y++) { v[y] = SP[base + y*17]; acc[y] = 0.f; }
#pragma unroll
        for (int yp = 0; yp < 16; yp++)
#pragma unroll
            for (int y = 0; y < 16; y++) {
                int d = (y > yp) ? (y - yp) : (yp - y);
                acc[y] = fmaf(g32[d], v[yp], acc[y]);
            }
#pragma unroll
        for (int y = 0; y < 16; y++) SP[base + y*17] = acc[y];
    }
    __syncthreads();
    // x-pass: 256 columns (y,z), 2 threads/column; h wave-uniform (tid>>8)
    // so all g32 indices stay compile-time constants (no scratch spill).
    {
        int c = tid & 255, h = tid >> 8;
        int base = (c >> 4) * 17 + (c & 15);     // 17*y + z
        float v[32];
#pragma unroll
        for (int xp = 0; xp < 32; xp++) v[xp] = SP[base + xp*272];
        float acc[16];
#pragma unroll
        for (int x0 = 0; x0 < 16; x0++) acc[x0] = 0.f;
        if (h == 0) {
#pragma unroll
            for (int xp = 0; xp < 32; xp++)
#pragma unroll
                for (int x0 = 0; x0 < 16; x0++) {
                    int d = (x0 > xp) ? (x0 - xp) : (xp - x0);
                    acc[x0] = fmaf(g32[d], v[xp], acc[x0]);
                }
#pragma unroll
            for (int x0 = 0; x0 < 16; x0++) {
                int n = x0*256 + c;
                float w = w0 ? w0[n] : 1.f;
                if (w1) w *= w1[n];
                outp[n] = w * acc[x0];
            }
        } else {
#pragma unroll
            for (int xp = 0; xp < 32; xp++)
#pragma unroll
                for (int x0 = 0; x0 < 16; x0++) {
                    int x = x0 + 16;
                    int d = (x > xp) ? (x - xp) : (xp - x);
                    acc[x0] = fmaf(g32[d], v[xp], acc[x0]);
                }
#pragma unroll
            for (int x0 = 0; x0 < 16; x0++) {
                int n = (x0+16)*256 + c;
                float w = w0 ? w0[n] : 1.f;
                if (w1) w *= w1[n];
                outp[n] = w * acc[x0];
            }
        }
    }
}

// ---------------- phase A: basis + norm conv (premul M); spare blocks: s2 ---
__global__ __launch_bounds__(512) void k_phaseA(const float* __restrict__ feat,
                                                float* __restrict__ W) {
    __shared__ float SP[512 * 17];
    const int bid = blockIdx.x, tid = threadIdx.x;
    if (bid < 28) {
        const int a = AB_A[bid], b = AB_B[bid];
        const float ca = INVSQF[a], cb = INVSQF[b];
        for (int s = tid; s < NT; s += 512) {
            float g0 = feat[s] * 0.2f, g1 = feat[NT + s] * 0.2f;
            float eg = ex2(-0.5f * LOG2E * (g0*g0 + g1*g1));
            float pa = 1.f;
            for (int i = 0; i < a; i++) pa *= g0;    // a,b wave-uniform
            float pb = 1.f;
            for (int i = 0; i < b; i++) pb *= g1;
            float v = eg * pa * ca * pb * cb;
            W[(R_M + bid)*NT + s] = v;
            SP[(s >> 4)*17 + (s & 15)] = v;
        }
        conv3d_store512(SP, W + (R_CV + bid)*NT, W + (R_M + bid)*NT, nullptr, tid);
    } else {
        // blocks 28..31: closed-form scale2 (exact separable product)
#pragma unroll
        for (int i = 0; i < 4; i++) {
            int n = (bid - 28) * 2048 + i*512 + tid;
            int x = n >> 8, y = (n >> 4) & 15, z = n & 15;
            float Sx = 0.f, Sy = 0.f, Sz = 0.f;
            for (int j = 0; j < 32; j++) { float d = (float)(x-j)*INVA; Sx += ex2(-0.5f*d*d); }
            for (int j = 0; j < 16; j++) { float d = (float)(y-j)*INVA; Sy += ex2(-0.5f*d*d); }
            for (int j = 0; j < 16; j++) { float d = (float)(z-j)*INVA; Sz += ex2(-0.5f*d*d); }
            W[R_S2*NT + n] = rsqrtf(Sx * Sy * Sz);
        }
    }
}

// ---------------- init: rowsum -> s1, q0, u1, u2 (float4, 4 pts/thread) -----
__global__ __launch_bounds__(64) void k_init(float* __restrict__ W,
                                             const float* __restrict__ lu) {
    int p = blockIdx.x * 64 + threadIdx.x;       // float4 index, 0..2047
    const float4* W4c = (const float4*)W;
    float4* W4 = (float4*)W;
    float rs[4] = {0.f, 0.f, 0.f, 0.f};
#pragma unroll
    for (int ab = 0; ab < 28; ab++) {
        float4 v = W4c[(R_CV+ab)*NQ + p];        // pre-multiplied by M in phaseA
        rs[0]+=v.x; rs[1]+=v.y; rs[2]+=v.z; rs[3]+=v.w;
    }
    float4 s2v = W4c[R_S2*NQ + p];
    float s2a[4] = {s2v.x, s2v.y, s2v.z, s2v.w};
    float lu_[4][4];
#pragma unroll
    for (int o = 0; o < 4; o++) {
        float4 l = ((const float4*)lu)[o*NQ + p];
        lu_[o][0]=l.x; lu_[o][1]=l.y; lu_[o][2]=l.z; lu_[o][3]=l.w;
    }
    float s1a[4], u1_[4][4], u2_[4][4];
#pragma unroll
    for (int L = 0; L < 4; L++) {
        float s1 = rsqrtf(rs[L]);
        s1a[L] = s1;
        float l0=lu_[0][L], l1=lu_[1][L], l2=lu_[2][L], l3=lu_[3][L];
        float mx = fmaxf(fmaxf(l0,l1), fmaxf(l2,l3));
        float q0=__expf(l0-mx), q1=__expf(l1-mx), q2=__expf(l2-mx), q3=__expf(l3-mx);
        float inv = 1.f / (q0+q1+q2+q3);
        q0*=inv; q1*=inv; q2*=inv; q3*=inv;
        float s2 = s2a[L];
        u1_[0][L]=q0*s1; u1_[1][L]=q1*s1; u1_[2][L]=q2*s1; u1_[3][L]=q3*s1;
        u2_[0][L]=q0*s2; u2_[1][L]=q1*s2; u2_[2][L]=q2*s2; u2_[3][L]=q3*s2;
    }
    W4[R_S1*NQ + p] = make_float4(s1a[0], s1a[1], s1a[2], s1a[3]);
#pragma unroll
    for (int c = 0; c < 4; c++) {
        W4[(R_U1+c)*NQ + p] = make_float4(u1_[c][0], u1_[c][1], u1_[c][2], u1_[c][3]);
        W4[(R_U2+c)*NQ + p] = make_float4(u2_[c][0], u2_[c][1], u2_[c][2], u2_[c][3]);
    }
}

// ---------------- iteration conv: 116 volumes; epilogue premul s*M ----------
__global__ __launch_bounds__(512) void k_conv(const float* __restrict__ W,
                                              float* __restrict__ Wout) {
    __shared__ float SP[512 * 17];
    const int idx = blockIdx.x;
    const int tid = threadIdx.x;
    if (idx < 112) {
        const float4* M4 = (const float4*)(W + (R_M + (idx >> 2))*NT);
        const float4* U4 = (const float4*)(W + (R_U1 + (idx & 3))*NT);
#pragma unroll
        for (int i = 0; i < 4; i++) {
            int s4 = tid + i*512;                // float4 index; s = 4*s4
            float4 m = M4[s4], u = U4[s4];
            int s = s4 << 2;
            int base = (s >> 4)*17 + (s & 15);   // s&15 in {0,4,8,12}: same row
            SP[base+0] = m.x*u.x; SP[base+1] = m.y*u.y;
            SP[base+2] = m.z*u.z; SP[base+3] = m.w*u.w;
        }
        // out = s1(n)*M(n)*conv  -> fuse contract becomes a plain sum
        conv3d_store512(SP, Wout + (R_CV + idx)*NT,
                        W + (R_M + (idx >> 2))*NT, W + R_S1*NT, tid);
    } else {
        const float4* U4 = (const float4*)(W + (R_U2 + (idx - 112))*NT);
#pragma unroll
        for (int i = 0; i < 4; i++) {
            int s4 = tid + i*512;
            float4 u = U4[s4];
            int s = s4 << 2;
            int base = (s >> 4)*17 + (s & 15);
            SP[base+0] = u.x; SP[base+1] = u.y; SP[base+2] = u.z; SP[base+3] = u.w;
        }
        // out = s2(n)*conv
        conv3d_store512(SP, Wout + (R_CV + idx)*NT, W + R_S2*NT, nullptr, tid);
    }
}

// ---------------- fuse: 29-term sum, compat, softmax (float4, 4 pts/thread) -
__global__ __launch_bounds__(64) void k_fuse(float* __restrict__ W,
        const float* __restrict__ lu, const float* __restrict__ compat,
        float* __restrict__ out, int last) {
    int p = blockIdx.x * 64 + threadIdx.x;       // float4 index, 0..2047
    const float4* W4c = (const float4*)W;
    float4* W4 = (float4*)W;
    float comb[4][4] = {{0.f,0.f,0.f,0.f},{0.f,0.f,0.f,0.f},
                        {0.f,0.f,0.f,0.f},{0.f,0.f,0.f,0.f}};   // [c][lane]
#pragma unroll
    for (int ab = 0; ab < 28; ab++)
#pragma unroll
        for (int c = 0; c < 4; c++) {
            float4 v = W4c[(R_CV + ab*4 + c)*NQ + p];   // premul s1*M in conv
            comb[c][0]+=v.x; comb[c][1]+=v.y; comb[c][2]+=v.z; comb[c][3]+=v.w;
        }
#pragma unroll
    for (int c = 0; c < 4; c++) {
        float4 v = W4c[(R_CV + 112 + c)*NQ + p];        // premul s2 in conv
        comb[c][0]+=v.x; comb[c][1]+=v.y; comb[c][2]+=v.z; comb[c][3]+=v.w;
    }
    float cmp[16];
#pragma unroll
    for (int i = 0; i < 16; i++) cmp[i] = compat[i];
    float lu_[4][4];
#pragma unroll
    for (int o = 0; o < 4; o++) {
        float4 l = ((const float4*)lu)[o*NQ + p];
        lu_[o][0]=l.x; lu_[o][1]=l.y; lu_[o][2]=l.z; lu_[o][3]=l.w;
    }
    float qq[4][4];                               // [c][lane]
#pragma unroll
    for (int L = 0; L < 4; L++) {
        float q[4];
#pragma unroll
        for (int o = 0; o < 4; o++) {
            float upd = 0.f;
#pragma unroll
            for (int c = 0; c < 4; c++) upd = fmaf(cmp[o*4+c], comb[c][L], upd);
            q[o] = lu_[o][L] - upd;
        }
        float mx = fmaxf(fmaxf(q[0],q[1]), fmaxf(q[2],q[3]));
        float sum = 0.f;
#pragma unroll
        for (int c = 0; c < 4; c++) { q[c] = __expf(q[c]-mx); sum += q[c]; }
        float inv = 1.f / sum;
#pragma unroll
        for (int c = 0; c < 4; c++) qq[c][L] = q[c] * inv;
    }
    if (last) {
#pragma unroll
        for (int c = 0; c < 4; c++)
            ((float4*)out)[c*NQ + p] = make_float4(qq[c][0], qq[c][1], qq[c][2], qq[c][3]);
    } else {
        float4 s1v = W4c[R_S1*NQ + p], s2v = W4c[R_S2*NQ + p];
        float s1a[4] = {s1v.x, s1v.y, s1v.z, s1v.w};
        float s2a[4] = {s2v.x, s2v.y, s2v.z, s2v.w};
#pragma unroll
        for (int c = 0; c < 4; c++) {
            W4[(R_U1+c)*NQ + p] = make_float4(qq[c][0]*s1a[0], qq[c][1]*s1a[1],
                                              qq[c][2]*s1a[2], qq[c][3]*s1a[3]);
            W4[(R_U2+c)*NQ + p] = make_float4(qq[c][0]*s2a[0], qq[c][1]*s2a[1],
                                              qq[c][2]*s2a[2], qq[c][3]*s2a[3]);
        }
    }
}

// ---------------------------------------------------------------- driver
extern "C" void kernel_launch(void* const* d_in, const int* in_sizes, int n_in,
                              void* d_out, int out_size, void* d_ws, size_t ws_size,
                              hipStream_t stream) {
    const float* lu     = (const float*)d_in[0];
    const float* feat   = (const float*)d_in[1];
    const float* compat = (const float*)d_in[2];
    float* out = (float*)d_out;
    float* W   = (float*)d_ws;     // needs 158*NT*4 = 5.2 MB

    k_phaseA<<<dim3(32),  dim3(512), 0, stream>>>(feat, W);   // basis+norm conv+s2
    k_init  <<<dim3(32),  dim3(64),  0, stream>>>(W, lu);     // s1, q0, u1, u2
    for (int it = 0; it < 5; it++) {
        k_conv<<<dim3(116), dim3(512), 0, stream>>>(W, W);
        k_fuse<<<dim3(32),  dim3(64),  0, stream>>>(W, lu, compat, out, it == 4);
    }
}

// Round 11
// 129.671 us; speedup vs baseline: 1.3611x; 1.2188x over previous
//
#include <hip/hip_runtime.h>
#include <math.h>

// CRF mean-field, fully factorized — NO O(N^2) pass.
// MULTI-LAUNCH, 12 dispatches (structural minimum — R9 proved fuse-via-atomics
// regresses: cross-XCD atomics serialize at the coherence point, +9 us/conv.
// R2-R5 proved fences/sc1 likewise. Kernel boundaries are the only cheap
// cross-XCD coherence on MI355X).
// R10 lesson: init/fuse are L2-LATENCY-bound -> thread count (TLP) dominates
// load width (ILP); float4+64thr (32 waves) was 4x slower than scalar+8192thr.
// This round: R8 bodies exactly (scalar, 1 pt/thread), grid 64x128 (64 CUs).
// Conv epilogue pre-multiplies s1*M / s2 so k_fuse is a plain 29-term sum.
// Bilateral kernel rank-28 Taylor basis (degree 6), separable 3-D Gaussian
// convs, 5 mean-field iterations. N = 32*16*16 = 8192, C = 4.

constexpr int   NT    = 8192;
constexpr float LOG2E = 1.4426950408889634f;
constexpr float SQL2E = 1.2011224087864498f;     // sqrt(log2 e)
constexpr float INVA  = 0.2f * SQL2E;            // spatial prescale

// W rows (NT floats each):
//   0..27 : M[ab]   32..35 : u1[c]   36..39 : u2[c]
//   40 : scale1   41 : scale2   42..157 : conv outputs (pre-multiplied)
constexpr int R_M = 0, R_U1 = 32, R_U2 = 36, R_S1 = 40, R_S2 = 41, R_CV = 42;

static __device__ __forceinline__ float ex2(float x) {
    return __builtin_amdgcn_exp2f(x);
}

__constant__ float INVSQF[7] = {1.f, 1.f, 0.70710678f, 0.40824829f,
                                0.20412415f, 0.09128709f, 0.03726780f};
// ab -> (a,b) enumeration: for k=0..6, a=k..0, b=k-a (must match contract order)
__constant__ int AB_A[28] = {0, 1,0, 2,1,0, 3,2,1,0, 4,3,2,1,0,
                             5,4,3,2,1,0, 6,5,4,3,2,1,0};
__constant__ int AB_B[28] = {0, 0,1, 0,1,2, 0,1,2,3, 0,1,2,3,4,
                             0,1,2,3,4,5, 0,1,2,3,4,5,6};

// ---------------- separable 3-D Gaussian conv, 512-thread version -----------
// SP staged as SP[(n>>4)*17 + (n&15)]; caller stages, we sync first.
// Epilogue: out(n) = wrow0[n]*wrow1[n]*acc  (wrow1 may be null -> 1.0).
static __device__ __forceinline__ void conv3d_store512(float* SP,
                                                       float* __restrict__ outp,
                                                       const float* w0,
                                                       const float* w1,
                                                       int tid) {
    float g32[32];
#pragma unroll
    for (int d = 0; d < 32; d++) { float t = d * INVA; g32[d] = ex2(-0.5f*t*t); }
    __syncthreads();
    // z-pass: 512 rows (x,y), one per thread, stride 17
    {
        int r = tid;
        float v[16], acc[16];
#pragma unroll
        for (int z = 0; z < 16; z++) { v[z] = SP[r*17 + z]; acc[z] = 0.f; }
#pragma unroll
        for (int zp = 0; zp < 16; zp++)
#pragma unroll
            for (int z = 0; z < 16; z++) {
                int d = (z > zp) ? (z - zp) : (zp - z);
                acc[z] = fmaf(g32[d], v[zp], acc[z]);
            }
#pragma unroll
        for (int z = 0; z < 16; z++) SP[r*17 + z] = acc[z];
    }
    __syncthreads();
    // y-pass: 512 rows (x,z), one per thread, stride 17 between y's
    {
        int x = tid >> 4, z = tid & 15;
        int base = x * 272 + z;
        float v[16], acc[16];
#pragma unroll
        for (int y = 0; y < 16; y++) { v[y] = SP[base + y*17]; acc[y] = 0.f; }
#pragma unroll
        for (int yp = 0; yp < 16; yp++)
#pragma unroll
            for (int y = 0; y < 16; y++) {
                int d = (y > yp) ? (y - yp) : (yp - y);
                acc[y] = fmaf(g32[d], v[yp], acc[y]);
            }
#pragma unroll
        for (int y = 0; y < 16; y++) SP[base + y*17] = acc[y];
    }
    __syncthreads();
    // x-pass: 256 columns (y,z), 2 threads/column; h wave-uniform (tid>>8)
    // so all g32 indices stay compile-time constants (no scratch spill).
    {
        int c = tid & 255, h = tid >> 8;
        int base = (c >> 4) * 17 + (c & 15);     // 17*y + z
        float v[32];
#pragma unroll
        for (int xp = 0; xp < 32; xp++) v[xp] = SP[base + xp*272];
        float acc[16];
#pragma unroll
        for (int x0 = 0; x0 < 16; x0++) acc[x0] = 0.f;
        if (h == 0) {
#pragma unroll
            for (int xp = 0; xp < 32; xp++)
#pragma unroll
                for (int x0 = 0; x0 < 16; x0++) {
                    int d = (x0 > xp) ? (x0 - xp) : (xp - x0);
                    acc[x0] = fmaf(g32[d], v[xp], acc[x0]);
                }
#pragma unroll
            for (int x0 = 0; x0 < 16; x0++) {
                int n = x0*256 + c;
                float w = w0 ? w0[n] : 1.f;
                if (w1) w *= w1[n];
                outp[n] = w * acc[x0];
            }
        } else {
#pragma unroll
            for (int xp = 0; xp < 32; xp++)
#pragma unroll
                for (int x0 = 0; x0 < 16; x0++) {
                    int x = x0 + 16;
                    int d = (x > xp) ? (x - xp) : (xp - x);
                    acc[x0] = fmaf(g32[d], v[xp], acc[x0]);
                }
#pragma unroll
            for (int x0 = 0; x0 < 16; x0++) {
                int n = (x0+16)*256 + c;
                float w = w0 ? w0[n] : 1.f;
                if (w1) w *= w1[n];
                outp[n] = w * acc[x0];
            }
        }
    }
}

// ---------------- phase A: basis + norm conv (premul M); spare blocks: s2 ---
__global__ __launch_bounds__(512) void k_phaseA(const float* __restrict__ feat,
                                                float* __restrict__ W) {
    __shared__ float SP[512 * 17];
    const int bid = blockIdx.x, tid = threadIdx.x;
    if (bid < 28) {
        const int a = AB_A[bid], b = AB_B[bid];
        const float ca = INVSQF[a], cb = INVSQF[b];
        for (int s = tid; s < NT; s += 512) {
            float g0 = feat[s] * 0.2f, g1 = feat[NT + s] * 0.2f;
            float eg = ex2(-0.5f * LOG2E * (g0*g0 + g1*g1));
            float pa = 1.f;
            for (int i = 0; i < a; i++) pa *= g0;    // a,b wave-uniform
            float pb = 1.f;
            for (int i = 0; i < b; i++) pb *= g1;
            float v = eg * pa * ca * pb * cb;
            W[(R_M + bid)*NT + s] = v;
            SP[(s >> 4)*17 + (s & 15)] = v;
        }
        conv3d_store512(SP, W + (R_CV + bid)*NT, W + (R_M + bid)*NT, nullptr, tid);
    } else {
        // blocks 28..31: closed-form scale2 (exact separable product)
#pragma unroll
        for (int i = 0; i < 4; i++) {
            int n = (bid - 28) * 2048 + i*512 + tid;
            int x = n >> 8, y = (n >> 4) & 15, z = n & 15;
            float Sx = 0.f, Sy = 0.f, Sz = 0.f;
            for (int j = 0; j < 32; j++) { float d = (float)(x-j)*INVA; Sx += ex2(-0.5f*d*d); }
            for (int j = 0; j < 16; j++) { float d = (float)(y-j)*INVA; Sy += ex2(-0.5f*d*d); }
            for (int j = 0; j < 16; j++) { float d = (float)(z-j)*INVA; Sz += ex2(-0.5f*d*d); }
            W[R_S2*NT + n] = rsqrtf(Sx * Sy * Sz);
        }
    }
}

// ---------------- init: rowsum (plain sum) -> scale1, q0, u1, u2 ------------
// Scalar 1 pt/thread (R8 body); grid 64x128 spreads the same 8192 threads
// over 64 CUs (latency-bound: TLP > ILP, R10 lesson).
__global__ __launch_bounds__(128) void k_init(float* __restrict__ W,
                                              const float* __restrict__ lu) {
    int n = blockIdx.x * 128 + threadIdx.x;
    float rs = 0.f;
#pragma unroll
    for (int ab = 0; ab < 28; ab++)
        rs += W[(R_CV+ab)*NT + n];            // pre-multiplied by M in phaseA
    float s1 = rsqrtf(rs);
    float s2 = W[R_S2*NT + n];
    W[R_S1*NT + n] = s1;
    float l0 = lu[n], l1 = lu[NT+n], l2 = lu[2*NT+n], l3 = lu[3*NT+n];
    float mx = fmaxf(fmaxf(l0,l1), fmaxf(l2,l3));
    float q0 = __expf(l0-mx), q1 = __expf(l1-mx), q2 = __expf(l2-mx), q3 = __expf(l3-mx);
    float inv = 1.f / (q0+q1+q2+q3);
    q0*=inv; q1*=inv; q2*=inv; q3*=inv;
    W[(R_U1+0)*NT+n]=q0*s1; W[(R_U1+1)*NT+n]=q1*s1; W[(R_U1+2)*NT+n]=q2*s1; W[(R_U1+3)*NT+n]=q3*s1;
    W[(R_U2+0)*NT+n]=q0*s2; W[(R_U2+1)*NT+n]=q1*s2; W[(R_U2+2)*NT+n]=q2*s2; W[(R_U2+3)*NT+n]=q3*s2;
}

// ---------------- iteration conv: 116 volumes; epilogue premul s*M ----------
__global__ __launch_bounds__(512) void k_conv(const float* __restrict__ W,
                                              float* __restrict__ Wout) {
    __shared__ float SP[512 * 17];
    const int idx = blockIdx.x;
    const int tid = threadIdx.x;
    if (idx < 112) {
        const float4* M4 = (const float4*)(W + (R_M + (idx >> 2))*NT);
        const float4* U4 = (const float4*)(W + (R_U1 + (idx & 3))*NT);
#pragma unroll
        for (int i = 0; i < 4; i++) {
            int s4 = tid + i*512;                // float4 index; s = 4*s4
            float4 m = M4[s4], u = U4[s4];
            int s = s4 << 2;
            int base = (s >> 4)*17 + (s & 15);   // s&15 in {0,4,8,12}: same row
            SP[base+0] = m.x*u.x; SP[base+1] = m.y*u.y;
            SP[base+2] = m.z*u.z; SP[base+3] = m.w*u.w;
        }
        // out = s1(n)*M(n)*conv  -> fuse contract becomes a plain sum
        conv3d_store512(SP, Wout + (R_CV + idx)*NT,
                        W + (R_M + (idx >> 2))*NT, W + R_S1*NT, tid);
    } else {
        const float4* U4 = (const float4*)(W + (R_U2 + (idx - 112))*NT);
#pragma unroll
        for (int i = 0; i < 4; i++) {
            int s4 = tid + i*512;
            float4 u = U4[s4];
            int s = s4 << 2;
            int base = (s >> 4)*17 + (s & 15);
            SP[base+0] = u.x; SP[base+1] = u.y; SP[base+2] = u.z; SP[base+3] = u.w;
        }
        // out = s2(n)*conv
        conv3d_store512(SP, Wout + (R_CV + idx)*NT, W + R_S2*NT, nullptr, tid);
    }
}

// ---------------- fuse: 29-term sum, compat, softmax, next u ----------------
// Scalar 1 pt/thread (R8 body); grid 64x128 (see k_init comment).
__global__ __launch_bounds__(128) void k_fuse(float* __restrict__ W,
        const float* __restrict__ lu, const float* __restrict__ compat,
        float* __restrict__ out, int last) {
    int n = blockIdx.x * 128 + threadIdx.x;
    float comb[4] = {0.f, 0.f, 0.f, 0.f};
#pragma unroll
    for (int ab = 0; ab < 28; ab++)
#pragma unroll
        for (int c = 0; c < 4; c++)
            comb[c] += W[(R_CV + ab*4 + c)*NT + n];   // premul s1*M in conv
#pragma unroll
    for (int c = 0; c < 4; c++)
        comb[c] += W[(R_CV + 112 + c)*NT + n];        // premul s2 in conv
    float q[4];
#pragma unroll
    for (int o = 0; o < 4; o++) {
        float upd = 0.f;
#pragma unroll
        for (int c = 0; c < 4; c++) upd = fmaf(compat[o*4+c], comb[c], upd);
        q[o] = lu[o*NT+n] - upd;
    }
    float mx = fmaxf(fmaxf(q[0],q[1]), fmaxf(q[2],q[3]));
    float sum = 0.f;
#pragma unroll
    for (int c = 0; c < 4; c++) { q[c] = __expf(q[c]-mx); sum += q[c]; }
    float inv = 1.f / sum;
    if (last) {
#pragma unroll
        for (int c = 0; c < 4; c++) out[c*NT+n] = q[c] * inv;
    } else {
        float s1 = W[R_S1*NT + n], s2 = W[R_S2*NT + n];
#pragma unroll
        for (int c = 0; c < 4; c++) {
            float qq = q[c] * inv;
            W[(R_U1+c)*NT+n] = qq*s1;
            W[(R_U2+c)*NT+n] = qq*s2;
        }
    }
}

// ---------------------------------------------------------------- driver
extern "C" void kernel_launch(void* const* d_in, const int* in_sizes, int n_in,
                              void* d_out, int out_size, void* d_ws, size_t ws_size,
                              hipStream_t stream) {
    const float* lu     = (const float*)d_in[0];
    const float* feat   = (const float*)d_in[1];
    const float* compat = (const float*)d_in[2];
    float* out = (float*)d_out;
    float* W   = (float*)d_ws;     // needs 158*NT*4 = 5.2 MB

    k_phaseA<<<dim3(32),  dim3(512), 0, stream>>>(feat, W);   // basis+norm conv+s2
    k_init  <<<dim3(64),  dim3(128), 0, stream>>>(W, lu);     // s1, q0, u1, u2
    for (int it = 0; it < 5; it++) {
        k_conv<<<dim3(116), dim3(512), 0, stream>>>(W, W);
        k_fuse<<<dim3(64),  dim3(128), 0, stream>>>(W, lu, compat, out, it == 4);
    }
}